// Round 2
// baseline (1372.343 us; speedup 1.0000x reference)
//
#include <hip/hip_runtime.h>
#include <hip/hip_bf16.h>

// Problem constants (from reference)
#define NN   100000   // nodes
#define NE   600000   // edges
#define INC  128      // in channels
#define HC   128      // heads*per_head = 2*64
#define NH   2        // heads
#define TDIM 64       // time enc dim
#define MSGD 64       // msg dim
#define EDD  128      // edge_attr dim = TDIM + MSGD

#define EPB  64       // edges per block (K2 tile M)
#define NPB  64       // nodes per block (K1 tile M)
#define LDK  (EDD + 8)  // padded row (bf16 elems) for A operand tiles
#define LDC  (HC + 8)   // padded row for C tiles

typedef __hip_bfloat16 bf16;
typedef __attribute__((ext_vector_type(8))) short short8;
typedef __attribute__((ext_vector_type(4))) float floatx4;

static __device__ __forceinline__ bf16  f2b(float f) { return __float2bfloat16(f); }
static __device__ __forceinline__ float2 up2(unsigned u) {
    __hip_bfloat162 h = *reinterpret_cast<__hip_bfloat162*>(&u);
    return __bfloat1622float2(h);
}

// ---------------------------------------------------------------------------
// K0b: convert the 5 weight matrices to bf16 *MFMA B-fragment order*:
// wF[mat][k0g][nt][lane][j] = W[k][n]  with n = nt*16 + (lane&15),
//                                         k = k0g*32 + (lane>>4)*8 + j
// Also zeroes denom (folded k0).
// ---------------------------------------------------------------------------
__global__ __launch_bounds__(256) void k0b_frag(
    const float* __restrict__ Wq, const float* __restrict__ Wk,
    const float* __restrict__ Wv, const float* __restrict__ Wsk,
    const float* __restrict__ We, bf16* __restrict__ wF,
    float* __restrict__ denom)
{
    int tid = blockIdx.x * 256 + threadIdx.x;
    if (tid < NN * NH) denom[tid] = 0.0f;
    if (tid >= 5 * 16384) return;
    int mat  = tid >> 14;
    int pos  = tid & 16383;
    int j    = pos & 7;
    int lane = (pos >> 3) & 63;
    int nt   = (pos >> 9) & 7;
    int k0g  = pos >> 12;                 // 0..3
    int n = nt * 16 + (lane & 15);
    int k = k0g * 32 + (lane >> 4) * 8 + j;
    const float* W = (mat == 0) ? Wq : (mat == 1) ? Wk : (mat == 2) ? Wv : (mat == 3) ? Wsk : We;
    wF[tid] = f2b(W[k * 128 + n]);
}

// ---------------------------------------------------------------------------
// K1: node projections via MFMA. 64 nodes x 128 cols per block; g-loop over
// {Wq,Wk,Wv,Wskip}. B-fragments come straight from global wF (coalesced,
// L2-resident). Also zeroes out_acc for its nodes (folded k0).
// q/k/v -> bf16 (LDS-assembled coalesced stores); skip -> f32 into d_out.
// ---------------------------------------------------------------------------
__global__ __launch_bounds__(256) void k1_node_proj(
    const float* __restrict__ x, const bf16* __restrict__ wF,
    const float* __restrict__ bq, const float* __restrict__ bk,
    const float* __restrict__ bv, const float* __restrict__ bsk,
    bf16* __restrict__ qn, bf16* __restrict__ kn, bf16* __restrict__ vn,
    float* __restrict__ skipv, float* __restrict__ out_acc)
{
    __shared__ __align__(16) bf16 xs[NPB * LDK];    // 17.4 KB
    __shared__ __align__(16) bf16 outs[NPB * LDC];  // 17.4 KB
    __shared__ float bias_s[4 * HC];

    int tid = threadIdx.x;
    int lane = tid & 63, wave = tid >> 6;
    int n0node = blockIdx.x * NPB;

    // zero out_acc for this block's nodes (coalesced float4 stores)
    for (int idx = tid; idx < NPB * (HC / 4); idx += 256) {
        int node = n0node + (idx >> 5);
        if (node < NN)
            reinterpret_cast<float4*>(out_acc)[(size_t)node * 32 + (idx & 31)] =
                make_float4(0.f, 0.f, 0.f, 0.f);
    }

    // stage x tile as bf16 (A-operand layout [m][k], padded)
    for (int idx = tid; idx < NPB * (INC / 4); idx += 256) {
        int m = idx >> 5, c4 = idx & 31;
        int node = n0node + m;
        float4 v = (node < NN) ? reinterpret_cast<const float4*>(x)[(size_t)node * 32 + c4]
                               : make_float4(0.f, 0.f, 0.f, 0.f);
        union { bf16 h[4]; uint2 u; } pk;
        pk.h[0] = f2b(v.x); pk.h[1] = f2b(v.y); pk.h[2] = f2b(v.z); pk.h[3] = f2b(v.w);
        *reinterpret_cast<uint2*>(&xs[m * LDK + c4 * 4]) = pk.u;
    }
    for (int i = tid; i < 4 * HC; i += 256) {
        const float* B = (i < 128) ? bq : (i < 256) ? bk : (i < 384) ? bv : bsk;
        bias_s[i] = B[i & 127];
    }
    __syncthreads();

    bf16* Os[3] = {qn, kn, vn};
    int m0 = wave * 16, r = lane & 15, quad = lane >> 4;

    for (int g = 0; g < 4; ++g) {
        const short8* Bf = reinterpret_cast<const short8*>(wF + (size_t)g * 16384);

        floatx4 acc[8];
        #pragma unroll
        for (int i = 0; i < 8; ++i) acc[i] = (floatx4){0.f, 0.f, 0.f, 0.f};

        #pragma unroll
        for (int k0g = 0; k0g < 4; ++k0g) {
            short8 a = *reinterpret_cast<const short8*>(&xs[(m0 + r) * LDK + k0g * 32 + quad * 8]);
            #pragma unroll
            for (int nt = 0; nt < 8; ++nt) {
                short8 b = Bf[(k0g * 8 + nt) * 64 + lane];
                acc[nt] = __builtin_amdgcn_mfma_f32_16x16x32_bf16(a, b, acc[nt], 0, 0, 0);
            }
        }

        if (g < 3) {
            // C layout: col=lane&15, row=quad*4+reg -> assemble in LDS, coalesced store
            #pragma unroll
            for (int nt = 0; nt < 8; ++nt) {
                int col = nt * 16 + r;
                float bsv = bias_s[g * HC + col];
                #pragma unroll
                for (int rg = 0; rg < 4; ++rg) {
                    int row = m0 + quad * 4 + rg;
                    outs[row * LDC + col] = f2b(acc[nt][rg] + bsv);
                }
            }
            __syncthreads();
            bf16* dst = Os[g];
            for (int idx = tid; idx < NPB * (HC / 8); idx += 256) {
                int row = idx >> 4, seg = idx & 15;
                int node = n0node + row;
                if (node < NN)
                    *reinterpret_cast<uint4*>(dst + (size_t)node * HC + seg * 8) =
                        *reinterpret_cast<const uint4*>(&outs[row * LDC + seg * 8]);
            }
            __syncthreads();
        } else {
            // skip connection: f32 direct stores into d_out
            #pragma unroll
            for (int nt = 0; nt < 8; ++nt) {
                int col = nt * 16 + r;
                float bsv = bias_s[3 * HC + col];
                #pragma unroll
                for (int rg = 0; rg < 4; ++rg) {
                    int node = n0node + m0 + quad * 4 + rg;
                    if (node < NN) skipv[(size_t)node * HC + col] = acc[nt][rg] + bsv;
                }
            }
        }
    }
}

// ---------------------------------------------------------------------------
// K2 (fused): per 64-edge block:
//   e = [cos(rel*wt+bt), msg] @ We  (MFMA, B-fragments from global)
//   ex = exp(q[dst].(k[src]+e)/8)   (no-max softmax: exact math identity)
//   atomicAdd out_acc[dst] += ex*(v[src]+e);  atomicAdd denom[dst,h] += ex
// Epilogue v2 (ILP): 2 edges per wave-iter (8 iters), 4-level shuffle reduce,
// all 24 q/k/v gathers prefetched into registers before the compute loop.
// ---------------------------------------------------------------------------
__global__ __launch_bounds__(256) void k2_fused(
    const int* __restrict__ eidx,
    const float* __restrict__ lu, const float* __restrict__ t, const float* __restrict__ msg,
    const float* __restrict__ wtv, const float* __restrict__ btv,
    const bf16* __restrict__ wFe,
    const bf16* __restrict__ qn, const bf16* __restrict__ kn, const bf16* __restrict__ vn,
    float* __restrict__ out_acc, float* __restrict__ denom)
{
    __shared__ __align__(16) bf16 tile[EPB * LDK];  // edge_attr, then aliased e  (17.4 KB)
    __shared__ float wt_s[TDIM], bt_s[TDIM];
    __shared__ float rel_s[EPB];
    __shared__ int src_s[EPB], dst_s[EPB];

    int tid = threadIdx.x;
    int lane = tid & 63, wave = tid >> 6;
    int e0 = blockIdx.x * EPB;   // NE % EPB == 0, no guards needed

    if (tid < TDIM) { wt_s[tid] = wtv[tid]; bt_s[tid] = btv[tid]; }
    if (tid < EPB) {
        int s = eidx[e0 + tid];
        int d = eidx[NE + e0 + tid];
        src_s[tid] = s; dst_s[tid] = d;
        rel_s[tid] = lu[s] - t[e0 + tid];
    }
    __syncthreads();

    // build edge_attr tile (bf16, A-operand layout); msg half vectorized
    for (int idx = tid; idx < EPB * (EDD / 4); idx += 256) {
        int m = idx >> 5, c4 = idx & 31;
        union { bf16 h[4]; uint2 u; } pk;
        if (c4 < 16) {
            float rv = rel_s[m];
            #pragma unroll
            for (int j = 0; j < 4; ++j) {
                int d = c4 * 4 + j;
                pk.h[j] = f2b(cosf(fmaf(rv, wt_s[d], bt_s[d])));
            }
        } else {
            float4 v = reinterpret_cast<const float4*>(msg)[(size_t)(e0 + m) * (MSGD / 4) + (c4 - 16)];
            pk.h[0] = f2b(v.x); pk.h[1] = f2b(v.y); pk.h[2] = f2b(v.z); pk.h[3] = f2b(v.w);
        }
        *reinterpret_cast<uint2*>(&tile[m * LDK + c4 * 4]) = pk.u;
    }
    __syncthreads();

    int m0 = wave * 16, r = lane & 15, quad = lane >> 4;
    const short8* Bf = reinterpret_cast<const short8*>(wFe);

    floatx4 acc[8];
    #pragma unroll
    for (int i = 0; i < 8; ++i) acc[i] = (floatx4){0.f, 0.f, 0.f, 0.f};

    #pragma unroll
    for (int k0g = 0; k0g < 4; ++k0g) {
        short8 a = *reinterpret_cast<const short8*>(&tile[(m0 + r) * LDK + k0g * 32 + quad * 8]);
        #pragma unroll
        for (int nt = 0; nt < 8; ++nt) {
            short8 b = Bf[(k0g * 8 + nt) * 64 + lane];
            acc[nt] = __builtin_amdgcn_mfma_f32_16x16x32_bf16(a, b, acc[nt], 0, 0, 0);
        }
    }

    // e tile -> LDS, aliased over edge_attr rows. Wave w reads (A-frags) and
    // writes (e) ONLY rows [m0, m0+16) -> within-wave ordering suffices.
    #pragma unroll
    for (int nt = 0; nt < 8; ++nt) {
        int col = nt * 16 + r;
        #pragma unroll
        for (int rg = 0; rg < 4; ++rg) {
            tile[(m0 + quad * 4 + rg) * LDK + col] = f2b(acc[nt][rg]);
        }
    }

    // ---- fused epilogue: 2 edges per iter; lane owns 4 channels (8B) ----
    int l5   = lane & 31;       // lane within edge
    int half = lane >> 5;       // which edge of the pair
    int hgrp = l5 >> 4;         // head of this lane's channels
    int c0   = l5 * 4;          // first channel (0..124)

    // prefetch ALL gathers into registers (statically indexed, full unroll)
    uint2 qv[8], kv[8], vv[8];
    int   dn[8], mm[8];
    #pragma unroll
    for (int i = 0; i < 8; ++i) {
        int m = m0 + 2 * i + half;
        int srcn = src_s[m], dstn = dst_s[m];
        mm[i] = m; dn[i] = dstn;
        qv[i] = *reinterpret_cast<const uint2*>(&qn[(size_t)dstn * HC + c0]);
        kv[i] = *reinterpret_cast<const uint2*>(&kn[(size_t)srcn * HC + c0]);
        vv[i] = *reinterpret_cast<const uint2*>(&vn[(size_t)srcn * HC + c0]);
    }

    #pragma unroll
    for (int i = 0; i < 8; ++i) {
        uint2 eu = *reinterpret_cast<const uint2*>(&tile[mm[i] * LDK + c0]);
        float2 e01 = up2(eu.x), e23 = up2(eu.y);
        float2 q01 = up2(qv[i].x), q23 = up2(qv[i].y);
        float2 k01 = up2(kv[i].x), k23 = up2(kv[i].y);
        float2 v01 = up2(vv[i].x), v23 = up2(vv[i].y);

        float s0 = k01.x + e01.x, s1 = k01.y + e01.y;
        float s2 = k23.x + e23.x, s3 = k23.y + e23.y;
        float part = q01.x * s0 + q01.y * s1 + q23.x * s2 + q23.y * s3;
        part += __shfl_xor(part, 1);
        part += __shfl_xor(part, 2);
        part += __shfl_xor(part, 4);
        part += __shfl_xor(part, 8);       // all 16 lanes of head group hold dot
        float ex = __expf(part * 0.125f);  // 1/sqrt(64)

        float* ob = &out_acc[(size_t)dn[i] * HC + c0];
        atomicAdd(ob + 0, ex * (v01.x + e01.x));
        atomicAdd(ob + 1, ex * (v01.y + e01.y));
        atomicAdd(ob + 2, ex * (v23.x + e23.x));
        atomicAdd(ob + 3, ex * (v23.y + e23.y));
        if ((l5 & 15) == 0) atomicAdd(&denom[dn[i] * NH + hgrp], ex);
    }
}

// ---------------------------------------------------------------------------
// K5: out = skip (already in d_out) + out_acc / denom
// ---------------------------------------------------------------------------
__global__ __launch_bounds__(256) void k5_final(
    const float* __restrict__ out_acc, const float* __restrict__ denom,
    float* __restrict__ out)
{
    int tid = blockIdx.x * 256 + threadIdx.x;
    if (tid >= NN * HC) return;
    int node = tid >> 7, h = (tid >> 6) & 1;
    out[tid] = out[tid] + out_acc[tid] / (denom[node * NH + h] + 1e-16f);
}

// ---------------------------------------------------------------------------
extern "C" void kernel_launch(void* const* d_in, const int* in_sizes, int n_in,
                              void* d_out, int out_size, void* d_ws, size_t ws_size,
                              hipStream_t stream)
{
    const float* x   = (const float*)d_in[0];
    const float* lu  = (const float*)d_in[1];
    const int*   eidx= (const int*)d_in[2];
    const float* t   = (const float*)d_in[3];
    const float* msg = (const float*)d_in[4];
    const float* wt  = (const float*)d_in[5];
    const float* bt  = (const float*)d_in[6];
    const float* Wq  = (const float*)d_in[7];
    const float* bq  = (const float*)d_in[8];
    const float* Wk  = (const float*)d_in[9];
    const float* bk  = (const float*)d_in[10];
    const float* Wv  = (const float*)d_in[11];
    const float* bv  = (const float*)d_in[12];
    const float* We  = (const float*)d_in[13];
    const float* Wsk = (const float*)d_in[14];
    const float* bsk = (const float*)d_in[15];
    float* out = (float*)d_out;

    // workspace layout (all offsets 16B-aligned)
    char* ws = (char*)d_ws;
    size_t off = 0;
    bf16*  qn      = (bf16*)(ws + off);  off += (size_t)NN * HC * 2;       // 25.6 MB
    bf16*  kn      = (bf16*)(ws + off);  off += (size_t)NN * HC * 2;       // 25.6 MB
    bf16*  vn      = (bf16*)(ws + off);  off += (size_t)NN * HC * 2;       // 25.6 MB
    float* out_acc = (float*)(ws + off); off += (size_t)NN * HC * 4;       // 51.2 MB
    float* denom   = (float*)(ws + off); off += (size_t)NN * NH * 4;       // 0.8 MB
    bf16*  wF      = (bf16*)(ws + off);  off += (size_t)5 * 128 * 128 * 2; // 0.16 MB

    k0b_frag<<<(NN * NH + 255) / 256, 256, 0, stream>>>(Wq, Wk, Wv, Wsk, We, wF, denom);

    k1_node_proj<<<(NN + NPB - 1) / NPB, 256, 0, stream>>>(
        x, wF, bq, bk, bv, bsk, qn, kn, vn, out, out_acc);

    k2_fused<<<NE / EPB, 256, 0, stream>>>(
        eidx, lu, t, msg, wt, bt, wF + (size_t)4 * 16384,
        qn, kn, vn, out_acc, denom);

    k5_final<<<(NN * HC + 255) / 256, 256, 0, stream>>>(out_acc, denom, out);
}

// Round 3
// 798.924 us; speedup vs baseline: 1.7177x; 1.7177x over previous
//
#include <hip/hip_runtime.h>
#include <hip/hip_bf16.h>

// Problem constants (from reference)
#define NN   100000   // nodes
#define NE   600000   // edges
#define INC  128      // in channels
#define HC   128      // heads*per_head = 2*64
#define NH   2        // heads
#define TDIM 64       // time enc dim
#define MSGD 64       // msg dim
#define EDD  128      // edge_attr dim = TDIM + MSGD

#define EPB  64       // edges per block (K2 tile M)
#define NPB  64       // nodes per block (K1 tile M)
#define LDK  (EDD + 8)  // padded row (bf16 elems) for A operand tiles
#define LDC  (HC + 8)   // padded row for C tiles
#define SCH  98         // scan chunk: 98*1024 >= NN

typedef __hip_bfloat16 bf16;
typedef __attribute__((ext_vector_type(8))) short short8;
typedef __attribute__((ext_vector_type(4))) float floatx4;

static __device__ __forceinline__ bf16  f2b(float f) { return __float2bfloat16(f); }
static __device__ __forceinline__ float2 bload2(const bf16* p) {
    __hip_bfloat162 h = *reinterpret_cast<const __hip_bfloat162*>(p);
    return __bfloat1622float2(h);
}

// ---------------------------------------------------------------------------
// K0b: weights -> bf16 MFMA B-fragment order; also zero denom and cnt.
// wF[mat][k0g][nt][lane][j] = W[k][n], n = nt*16+(lane&15), k = k0g*32+(lane>>4)*8+j
// ---------------------------------------------------------------------------
__global__ __launch_bounds__(256) void k0b_frag(
    const float* __restrict__ Wq, const float* __restrict__ Wk,
    const float* __restrict__ Wv, const float* __restrict__ Wsk,
    const float* __restrict__ We, bf16* __restrict__ wF,
    float* __restrict__ denom, int* __restrict__ cnt)
{
    int tid = blockIdx.x * 256 + threadIdx.x;
    if (tid < NN * NH) denom[tid] = 0.0f;
    if (tid < NN) cnt[tid] = 0;
    if (tid >= 5 * 16384) return;
    int mat  = tid >> 14;
    int pos  = tid & 16383;
    int j    = pos & 7;
    int lane = (pos >> 3) & 63;
    int nt   = (pos >> 9) & 7;
    int k0g  = pos >> 12;                 // 0..3
    int n = nt * 16 + (lane & 15);
    int k = k0g * 32 + (lane >> 4) * 8 + j;
    const float* W = (mat == 0) ? Wq : (mat == 1) ? Wk : (mat == 2) ? Wv : (mat == 3) ? Wsk : We;
    wF[tid] = f2b(W[k * 128 + n]);
}

// ---------------------------------------------------------------------------
// Counting sort of edges by dst: histogram -> 1-block scan -> scatter.
// Gives perm[] s.t. dst[perm[i]] is non-decreasing; k2 then merges runs.
// ---------------------------------------------------------------------------
__global__ __launch_bounds__(256) void kh_hist(const int* __restrict__ eidx, int* __restrict__ cnt)
{
    int e = blockIdx.x * 256 + threadIdx.x;
    if (e < NE) atomicAdd(&cnt[eidx[NE + e]], 1);
}

__global__ __launch_bounds__(1024) void ks_scan(const int* __restrict__ cnt, int* __restrict__ cursor)
{
    __shared__ int part[1024];
    int i = threadIdx.x;
    int base = i * SCH;
    int s = 0;
    for (int j = 0; j < SCH; ++j) { int idx = base + j; if (idx < NN) s += cnt[idx]; }
    part[i] = s;
    __syncthreads();
    // inclusive Hillis-Steele scan over 1024 partials
    for (int off = 1; off < 1024; off <<= 1) {
        int v = (i >= off) ? part[i - off] : 0;
        __syncthreads();
        part[i] += v;
        __syncthreads();
    }
    int run = part[i] - s;   // exclusive prefix at chunk start
    for (int j = 0; j < SCH; ++j) {
        int idx = base + j;
        if (idx < NN) { cursor[idx] = run; run += cnt[idx]; }
    }
}

__global__ __launch_bounds__(256) void kp_scatter(
    const int* __restrict__ eidx, int* __restrict__ cursor, int* __restrict__ perm)
{
    int e = blockIdx.x * 256 + threadIdx.x;
    if (e < NE) {
        int p = atomicAdd(&cursor[eidx[NE + e]], 1);
        perm[p] = e;
    }
}

// ---------------------------------------------------------------------------
// K1: node projections via MFMA. 64 nodes x 128 cols per block; g-loop over
// {Wq,Wk,Wv,Wskip}. B-fragments from global wF (coalesced, L2-resident).
// Also zeroes out_acc for its nodes. q/k/v -> bf16; skip -> f32 into d_out.
// ---------------------------------------------------------------------------
__global__ __launch_bounds__(256) void k1_node_proj(
    const float* __restrict__ x, const bf16* __restrict__ wF,
    const float* __restrict__ bq, const float* __restrict__ bk,
    const float* __restrict__ bv, const float* __restrict__ bsk,
    bf16* __restrict__ qn, bf16* __restrict__ kn, bf16* __restrict__ vn,
    float* __restrict__ skipv, float* __restrict__ out_acc)
{
    __shared__ __align__(16) bf16 xs[NPB * LDK];    // 17.4 KB
    __shared__ __align__(16) bf16 outs[NPB * LDC];  // 17.4 KB
    __shared__ float bias_s[4 * HC];

    int tid = threadIdx.x;
    int lane = tid & 63, wave = tid >> 6;
    int n0node = blockIdx.x * NPB;

    // zero out_acc for this block's nodes (coalesced float4 stores)
    for (int idx = tid; idx < NPB * (HC / 4); idx += 256) {
        int node = n0node + (idx >> 5);
        if (node < NN)
            reinterpret_cast<float4*>(out_acc)[(size_t)node * 32 + (idx & 31)] =
                make_float4(0.f, 0.f, 0.f, 0.f);
    }

    // stage x tile as bf16 (A-operand layout [m][k], padded)
    for (int idx = tid; idx < NPB * (INC / 4); idx += 256) {
        int m = idx >> 5, c4 = idx & 31;
        int node = n0node + m;
        float4 v = (node < NN) ? reinterpret_cast<const float4*>(x)[(size_t)node * 32 + c4]
                               : make_float4(0.f, 0.f, 0.f, 0.f);
        union { bf16 h[4]; uint2 u; } pk;
        pk.h[0] = f2b(v.x); pk.h[1] = f2b(v.y); pk.h[2] = f2b(v.z); pk.h[3] = f2b(v.w);
        *reinterpret_cast<uint2*>(&xs[m * LDK + c4 * 4]) = pk.u;
    }
    for (int i = tid; i < 4 * HC; i += 256) {
        const float* B = (i < 128) ? bq : (i < 256) ? bk : (i < 384) ? bv : bsk;
        bias_s[i] = B[i & 127];
    }
    __syncthreads();

    bf16* Os[3] = {qn, kn, vn};
    int m0 = wave * 16, r = lane & 15, quad = lane >> 4;

    for (int g = 0; g < 4; ++g) {
        const short8* Bf = reinterpret_cast<const short8*>(wF + (size_t)g * 16384);

        floatx4 acc[8];
        #pragma unroll
        for (int i = 0; i < 8; ++i) acc[i] = (floatx4){0.f, 0.f, 0.f, 0.f};

        #pragma unroll
        for (int k0g = 0; k0g < 4; ++k0g) {
            short8 a = *reinterpret_cast<const short8*>(&xs[(m0 + r) * LDK + k0g * 32 + quad * 8]);
            #pragma unroll
            for (int nt = 0; nt < 8; ++nt) {
                short8 b = Bf[(k0g * 8 + nt) * 64 + lane];
                acc[nt] = __builtin_amdgcn_mfma_f32_16x16x32_bf16(a, b, acc[nt], 0, 0, 0);
            }
        }

        if (g < 3) {
            // C layout: col=lane&15, row=quad*4+reg -> assemble in LDS, coalesced store
            #pragma unroll
            for (int nt = 0; nt < 8; ++nt) {
                int col = nt * 16 + r;
                float bsv = bias_s[g * HC + col];
                #pragma unroll
                for (int rg = 0; rg < 4; ++rg) {
                    int row = m0 + quad * 4 + rg;
                    outs[row * LDC + col] = f2b(acc[nt][rg] + bsv);
                }
            }
            __syncthreads();
            bf16* dst = Os[g];
            for (int idx = tid; idx < NPB * (HC / 8); idx += 256) {
                int row = idx >> 4, seg = idx & 15;
                int node = n0node + row;
                if (node < NN)
                    *reinterpret_cast<uint4*>(dst + (size_t)node * HC + seg * 8) =
                        *reinterpret_cast<const uint4*>(&outs[row * LDC + seg * 8]);
            }
            __syncthreads();
        } else {
            // skip connection: f32 direct stores into d_out
            #pragma unroll
            for (int nt = 0; nt < 8; ++nt) {
                int col = nt * 16 + r;
                float bsv = bias_s[3 * HC + col];
                #pragma unroll
                for (int rg = 0; rg < 4; ++rg) {
                    int node = n0node + m0 + quad * 4 + rg;
                    if (node < NN) skipv[(size_t)node * HC + col] = acc[nt][rg] + bsv;
                }
            }
        }
    }
}

// ---------------------------------------------------------------------------
// K2 (fused, dst-sorted): per 64-sorted-edge block:
//   e = [cos(rel*wt+bt), msg] @ We  (MFMA)
//   ex = exp(q[dst].(k[src]+e)/8)   (no-max softmax: exact identity)
//   register-accumulate ex*(v+e) per dst-run; atomic flush on dst change.
// Sorted order makes dst runs contiguous -> ~4x fewer out_acc atomics.
// ---------------------------------------------------------------------------
__global__ __launch_bounds__(256) void k2_fused(
    const int* __restrict__ eidx, const int* __restrict__ perm,
    const float* __restrict__ lu, const float* __restrict__ t, const float* __restrict__ msg,
    const float* __restrict__ wtv, const float* __restrict__ btv,
    const bf16* __restrict__ wFe,
    const bf16* __restrict__ qn, const bf16* __restrict__ kn, const bf16* __restrict__ vn,
    float* __restrict__ out_acc, float* __restrict__ denom)
{
    __shared__ __align__(16) bf16 tile[EPB * LDK];  // edge_attr, then aliased e  (17.4 KB)
    __shared__ float wt_s[TDIM], bt_s[TDIM];
    __shared__ float rel_s[EPB];
    __shared__ int src_s[EPB], dst_s[EPB], eid_s[EPB];

    int tid = threadIdx.x;
    int lane = tid & 63, wave = tid >> 6;
    int e0 = blockIdx.x * EPB;   // NE % EPB == 0, no guards needed

    if (tid < TDIM) { wt_s[tid] = wtv[tid]; bt_s[tid] = btv[tid]; }
    if (tid < EPB) {
        int es = perm[e0 + tid];          // original edge id, dst-sorted order
        int s = eidx[es];
        int d = eidx[NE + es];
        src_s[tid] = s; dst_s[tid] = d; eid_s[tid] = es;
        rel_s[tid] = lu[s] - t[es];
    }
    __syncthreads();

    // build edge_attr tile (bf16, A-operand layout); msg half vectorized
    for (int idx = tid; idx < EPB * (EDD / 4); idx += 256) {
        int m = idx >> 5, c4 = idx & 31;
        union { bf16 h[4]; uint2 u; } pk;
        if (c4 < 16) {
            float rv = rel_s[m];
            #pragma unroll
            for (int j = 0; j < 4; ++j) {
                int d = c4 * 4 + j;
                pk.h[j] = f2b(cosf(fmaf(rv, wt_s[d], bt_s[d])));
            }
        } else {
            float4 v = reinterpret_cast<const float4*>(msg)[(size_t)eid_s[m] * (MSGD / 4) + (c4 - 16)];
            pk.h[0] = f2b(v.x); pk.h[1] = f2b(v.y); pk.h[2] = f2b(v.z); pk.h[3] = f2b(v.w);
        }
        *reinterpret_cast<uint2*>(&tile[m * LDK + c4 * 4]) = pk.u;
    }
    __syncthreads();

    int m0 = wave * 16, r = lane & 15, quad = lane >> 4;
    const short8* Bf = reinterpret_cast<const short8*>(wFe);

    floatx4 acc[8];
    #pragma unroll
    for (int i = 0; i < 8; ++i) acc[i] = (floatx4){0.f, 0.f, 0.f, 0.f};

    #pragma unroll
    for (int k0g = 0; k0g < 4; ++k0g) {
        short8 a = *reinterpret_cast<const short8*>(&tile[(m0 + r) * LDK + k0g * 32 + quad * 8]);
        #pragma unroll
        for (int nt = 0; nt < 8; ++nt) {
            short8 b = Bf[(k0g * 8 + nt) * 64 + lane];
            acc[nt] = __builtin_amdgcn_mfma_f32_16x16x32_bf16(a, b, acc[nt], 0, 0, 0);
        }
    }

    // e tile -> LDS, aliased over edge_attr rows (wave-private rows -> safe)
    #pragma unroll
    for (int nt = 0; nt < 8; ++nt) {
        int col = nt * 16 + r;
        #pragma unroll
        for (int rg = 0; rg < 4; ++rg) {
            tile[(m0 + quad * 4 + rg) * LDK + col] = f2b(acc[nt][rg]);
        }
    }

    // ---- fused epilogue with dst-run merging ----
    // lane owns channels {2*lane, 2*lane+1}; lanes 0..31 head0, 32..63 head1
    int half = lane >> 5;
    int cur = dst_s[m0];
    float2 qv = bload2(&qn[(size_t)cur * HC + 2 * lane]);
    float a0 = 0.f, a1 = 0.f, aex = 0.f;

    for (int i = 0; i < 16; ++i) {
        int m = m0 + i;
        int srcn = src_s[m], dstn = dst_s[m];
        if (dstn != cur) {                      // wave-uniform branch
            float* ob = &out_acc[(size_t)cur * HC + 2 * lane];
            atomicAdd(ob + 0, a0);
            atomicAdd(ob + 1, a1);
            if ((lane & 31) == 0) atomicAdd(&denom[cur * NH + half], aex);
            a0 = a1 = aex = 0.f;
            cur = dstn;
            qv = bload2(&qn[(size_t)cur * HC + 2 * lane]);
        }
        float2 kv = bload2(&kn[(size_t)srcn * HC + 2 * lane]);
        float2 ev = bload2(&tile[m * LDK + 2 * lane]);
        float part = qv.x * (kv.x + ev.x) + qv.y * (kv.y + ev.y);
        part += __shfl_xor(part, 1);
        part += __shfl_xor(part, 2);
        part += __shfl_xor(part, 4);
        part += __shfl_xor(part, 8);
        part += __shfl_xor(part, 16);           // 32-lane head group holds dot
        float ex = __expf(part * 0.125f);       // 1/sqrt(64)
        float2 vv = bload2(&vn[(size_t)srcn * HC + 2 * lane]);
        a0 += ex * (vv.x + ev.x);
        a1 += ex * (vv.y + ev.y);
        aex += ex;
    }
    // final flush
    {
        float* ob = &out_acc[(size_t)cur * HC + 2 * lane];
        atomicAdd(ob + 0, a0);
        atomicAdd(ob + 1, a1);
        if ((lane & 31) == 0) atomicAdd(&denom[cur * NH + half], aex);
    }
}

// ---------------------------------------------------------------------------
// K5: out = skip (already in d_out) + out_acc / denom
// ---------------------------------------------------------------------------
__global__ __launch_bounds__(256) void k5_final(
    const float* __restrict__ out_acc, const float* __restrict__ denom,
    float* __restrict__ out)
{
    int tid = blockIdx.x * 256 + threadIdx.x;
    if (tid >= NN * HC) return;
    int node = tid >> 7, h = (tid >> 6) & 1;
    out[tid] = out[tid] + out_acc[tid] / (denom[node * NH + h] + 1e-16f);
}

// ---------------------------------------------------------------------------
extern "C" void kernel_launch(void* const* d_in, const int* in_sizes, int n_in,
                              void* d_out, int out_size, void* d_ws, size_t ws_size,
                              hipStream_t stream)
{
    const float* x   = (const float*)d_in[0];
    const float* lu  = (const float*)d_in[1];
    const int*   eidx= (const int*)d_in[2];
    const float* t   = (const float*)d_in[3];
    const float* msg = (const float*)d_in[4];
    const float* wt  = (const float*)d_in[5];
    const float* bt  = (const float*)d_in[6];
    const float* Wq  = (const float*)d_in[7];
    const float* bq  = (const float*)d_in[8];
    const float* Wk  = (const float*)d_in[9];
    const float* bk  = (const float*)d_in[10];
    const float* Wv  = (const float*)d_in[11];
    const float* bv  = (const float*)d_in[12];
    const float* We  = (const float*)d_in[13];
    const float* Wsk = (const float*)d_in[14];
    const float* bsk = (const float*)d_in[15];
    float* out = (float*)d_out;

    // workspace layout (all offsets 16B-aligned)
    char* ws = (char*)d_ws;
    size_t off = 0;
    bf16*  qn      = (bf16*)(ws + off);  off += (size_t)NN * HC * 2;       // 25.6 MB
    bf16*  kn      = (bf16*)(ws + off);  off += (size_t)NN * HC * 2;       // 25.6 MB
    bf16*  vn      = (bf16*)(ws + off);  off += (size_t)NN * HC * 2;       // 25.6 MB
    float* out_acc = (float*)(ws + off); off += (size_t)NN * HC * 4;       // 51.2 MB
    float* denom   = (float*)(ws + off); off += (size_t)NN * NH * 4;       // 0.8 MB
    bf16*  wF      = (bf16*)(ws + off);  off += (size_t)5 * 128 * 128 * 2; // 0.16 MB
    int*   cnt     = (int*)(ws + off);   off += (size_t)NN * 4;            // 0.4 MB (cursor after scan)
    int*   perm    = (int*)(ws + off);   off += (size_t)NE * 4;            // 2.4 MB

    k0b_frag<<<(NN * NH + 255) / 256, 256, 0, stream>>>(Wq, Wk, Wv, Wsk, We, wF, denom, cnt);

    kh_hist<<<(NE + 255) / 256, 256, 0, stream>>>(eidx, cnt);
    ks_scan<<<1, 1024, 0, stream>>>(cnt, cnt);   // in-place: cnt -> cursor(start offsets)
    kp_scatter<<<(NE + 255) / 256, 256, 0, stream>>>(eidx, cnt, perm);

    k1_node_proj<<<(NN + NPB - 1) / NPB, 256, 0, stream>>>(
        x, wF, bq, bk, bv, bsk, qn, kn, vn, out, out_acc);

    k2_fused<<<NE / EPB, 256, 0, stream>>>(
        eidx, perm, lu, t, msg, wt, bt, wF + (size_t)4 * 16384,
        qn, kn, vn, out_acc, denom);

    k5_final<<<(NN * HC + 255) / 256, 256, 0, stream>>>(out_acc, denom, out);
}

// Round 5
// 604.268 us; speedup vs baseline: 2.2711x; 1.3221x over previous
//
#include <hip/hip_runtime.h>
#include <hip/hip_bf16.h>

// Problem constants (from reference)
#define NN   100000   // nodes
#define NE   600000   // edges
#define INC  128      // in channels
#define HC   128      // heads*per_head = 2*64
#define NH   2        // heads
#define TDIM 64       // time enc dim
#define MSGD 64       // msg dim
#define EDD  128      // edge_attr dim = TDIM + MSGD

#define EPB  64       // edges per block (K2 tile M)
#define NPB  64       // nodes per block (K1 tile M)
#define LDK  (EDD + 8)  // padded row (bf16 elems) for A operand tiles
#define LDC  (HC + 8)   // padded row for C tiles
#define NSB  98         // scan blocks: 98*1024 >= NN

typedef __hip_bfloat16 bf16;
typedef __attribute__((ext_vector_type(8))) short short8;
typedef __attribute__((ext_vector_type(4))) float floatx4;

static __device__ __forceinline__ bf16  f2b(float f) { return __float2bfloat16(f); }
static __device__ __forceinline__ float2 bload2(const bf16* p) {
    __hip_bfloat162 h = *reinterpret_cast<const __hip_bfloat162*>(p);
    return __bfloat1622float2(h);
}

// ---------------------------------------------------------------------------
// K0b: weights -> bf16 MFMA B-fragment order; also zero denom and cnt.
// wF[mat][k0g][nt][lane][j] = W[k][n], n = nt*16+(lane&15), k = k0g*32+(lane>>4)*8+j
// ---------------------------------------------------------------------------
__global__ __launch_bounds__(256) void k0b_frag(
    const float* __restrict__ Wq, const float* __restrict__ Wk,
    const float* __restrict__ Wv, const float* __restrict__ Wsk,
    const float* __restrict__ We, bf16* __restrict__ wF,
    float* __restrict__ denom, int* __restrict__ cnt)
{
    int tid = blockIdx.x * 256 + threadIdx.x;
    if (tid < NN * NH) denom[tid] = 0.0f;
    if (tid < NN) cnt[tid] = 0;
    if (tid >= 5 * 16384) return;
    int mat  = tid >> 14;
    int pos  = tid & 16383;
    int j    = pos & 7;
    int lane = (pos >> 3) & 63;
    int nt   = (pos >> 9) & 7;
    int k0g  = pos >> 12;                 // 0..3
    int n = nt * 16 + (lane & 15);
    int k = k0g * 32 + (lane >> 4) * 8 + j;
    const float* W = (mat == 0) ? Wq : (mat == 1) ? Wk : (mat == 2) ? Wv : (mat == 3) ? Wsk : We;
    wF[tid] = f2b(W[k * 128 + n]);
}

// ---------------------------------------------------------------------------
// Counting sort of edges by dst: histogram -> parallel 3-pass scan -> scatter.
// ---------------------------------------------------------------------------
__global__ __launch_bounds__(256) void kh_hist(const int* __restrict__ eidx, int* __restrict__ cnt)
{
    int e = blockIdx.x * 256 + threadIdx.x;
    if (e < NE) atomicAdd(&cnt[eidx[NE + e]], 1);
}

// pass a: per-1024-chunk sums (98 blocks x 256 threads, 4 elems/thread)
__global__ __launch_bounds__(256) void ks_scan_a(const int* __restrict__ cnt, int* __restrict__ bsum)
{
    __shared__ int red[4];
    int b = blockIdx.x, tid = threadIdx.x;
    int base = b * 1024 + tid * 4;
    int s = 0;
    if (base + 3 < NN) {
        int4 q = *reinterpret_cast<const int4*>(&cnt[base]);
        s = q.x + q.y + q.z + q.w;
    } else {
        #pragma unroll
        for (int j = 0; j < 4; ++j) if (base + j < NN) s += cnt[base + j];
    }
    #pragma unroll
    for (int off = 1; off < 64; off <<= 1) s += __shfl_xor(s, off);
    if ((tid & 63) == 0) red[tid >> 6] = s;
    __syncthreads();
    if (tid == 0) bsum[b] = red[0] + red[1] + red[2] + red[3];
}

// pass b: 1 tiny block scans the 98 chunk sums -> exclusive prefixes
__global__ __launch_bounds__(128) void ks_scan_b(int* __restrict__ bsum)
{
    __shared__ int sh[128];
    int i = threadIdx.x;
    int v = (i < NSB) ? bsum[i] : 0;
    sh[i] = v;
    __syncthreads();
    for (int off = 1; off < 128; off <<= 1) {
        int u = (i >= off) ? sh[i - off] : 0;
        __syncthreads();
        sh[i] += u;
        __syncthreads();
    }
    if (i < NSB) bsum[i] = sh[i] - v;   // exclusive
}

// pass c: per-chunk exclusive scan + chunk offset -> cursor (in-place safe:
// each thread reads its own 4 elems before writing them)
__global__ __launch_bounds__(256) void ks_scan_c(
    const int* __restrict__ cnt, const int* __restrict__ bsum, int* __restrict__ cursor)
{
    __shared__ int tsum[256];
    int b = blockIdx.x, tid = threadIdx.x;
    int base = b * 1024 + tid * 4;
    int v0 = 0, v1 = 0, v2 = 0, v3 = 0;
    if (base + 3 < NN) {
        int4 q = *reinterpret_cast<const int4*>(&cnt[base]);
        v0 = q.x; v1 = q.y; v2 = q.z; v3 = q.w;
    } else {
        if (base     < NN) v0 = cnt[base];
        if (base + 1 < NN) v1 = cnt[base + 1];
        if (base + 2 < NN) v2 = cnt[base + 2];
        if (base + 3 < NN) v3 = cnt[base + 3];
    }
    int s = v0 + v1 + v2 + v3;
    tsum[tid] = s;
    __syncthreads();
    for (int off = 1; off < 256; off <<= 1) {
        int u = (tid >= off) ? tsum[tid - off] : 0;
        __syncthreads();
        tsum[tid] += u;
        __syncthreads();
    }
    int pre = tsum[tid] - s + bsum[b];   // exclusive prefix incl. chunk offset
    if (base     < NN) { cursor[base]     = pre; pre += v0; }
    if (base + 1 < NN) { cursor[base + 1] = pre; pre += v1; }
    if (base + 2 < NN) { cursor[base + 2] = pre; pre += v2; }
    if (base + 3 < NN) { cursor[base + 3] = pre; }
}

__global__ __launch_bounds__(256) void kp_scatter(
    const int* __restrict__ eidx, int* __restrict__ cursor, int* __restrict__ perm)
{
    int e = blockIdx.x * 256 + threadIdx.x;
    if (e < NE) {
        int p = atomicAdd(&cursor[eidx[NE + e]], 1);
        perm[p] = e;
    }
}

// ---------------------------------------------------------------------------
// K1: node projections via MFMA, ONE GEMM GROUP PER BLOCK (grid = 4 x 1563).
// g = blockIdx.x in {Wq,Wk,Wv,Wskip}; removes the serial g-loop + 6 barriers.
// x tile re-reads across g hit L3 (x fits easily). g==0 also zeroes out_acc.
// q/k/v -> bf16 (LDS-assembled coalesced stores); skip -> f32 into d_out.
// ---------------------------------------------------------------------------
__global__ __launch_bounds__(256) void k1_node_proj(
    const float* __restrict__ x, const bf16* __restrict__ wF,
    const float* __restrict__ bq, const float* __restrict__ bk,
    const float* __restrict__ bv, const float* __restrict__ bsk,
    bf16* __restrict__ qn, bf16* __restrict__ kn, bf16* __restrict__ vn,
    float* __restrict__ skipv, float* __restrict__ out_acc)
{
    __shared__ __align__(16) bf16 xs[NPB * LDK];    // 17.4 KB
    __shared__ __align__(16) bf16 outs[NPB * LDC];  // 17.4 KB
    __shared__ float bias_s[HC];

    int tid = threadIdx.x;
    int lane = tid & 63, wave = tid >> 6;
    int g = blockIdx.x;                  // 0..3
    int n0node = blockIdx.y * NPB;

    if (g == 0) {
        // zero out_acc for this block's nodes (coalesced float4 stores)
        for (int idx = tid; idx < NPB * (HC / 4); idx += 256) {
            int node = n0node + (idx >> 5);
            if (node < NN)
                reinterpret_cast<float4*>(out_acc)[(size_t)node * 32 + (idx & 31)] =
                    make_float4(0.f, 0.f, 0.f, 0.f);
        }
    }

    // stage x tile as bf16 (A-operand layout [m][k], padded)
    for (int idx = tid; idx < NPB * (INC / 4); idx += 256) {
        int m = idx >> 5, c4 = idx & 31;
        int node = n0node + m;
        float4 v = (node < NN) ? reinterpret_cast<const float4*>(x)[(size_t)node * 32 + c4]
                               : make_float4(0.f, 0.f, 0.f, 0.f);
        union { bf16 h[4]; uint2 u; } pk;
        pk.h[0] = f2b(v.x); pk.h[1] = f2b(v.y); pk.h[2] = f2b(v.z); pk.h[3] = f2b(v.w);
        *reinterpret_cast<uint2*>(&xs[m * LDK + c4 * 4]) = pk.u;
    }
    {
        const float* B = (g == 0) ? bq : (g == 1) ? bk : (g == 2) ? bv : bsk;
        if (tid < HC) bias_s[tid] = B[tid];
    }
    __syncthreads();

    int m0 = wave * 16, r = lane & 15, quad = lane >> 4;
    const short8* Bf = reinterpret_cast<const short8*>(wF + (size_t)g * 16384);

    floatx4 acc[8];
    #pragma unroll
    for (int i = 0; i < 8; ++i) acc[i] = (floatx4){0.f, 0.f, 0.f, 0.f};

    #pragma unroll
    for (int k0g = 0; k0g < 4; ++k0g) {
        short8 a = *reinterpret_cast<const short8*>(&xs[(m0 + r) * LDK + k0g * 32 + quad * 8]);
        #pragma unroll
        for (int nt = 0; nt < 8; ++nt) {
            short8 b = Bf[(k0g * 8 + nt) * 64 + lane];
            acc[nt] = __builtin_amdgcn_mfma_f32_16x16x32_bf16(a, b, acc[nt], 0, 0, 0);
        }
    }

    if (g < 3) {
        // C layout: col=lane&15, row=quad*4+reg -> assemble in LDS, coalesced store
        #pragma unroll
        for (int nt = 0; nt < 8; ++nt) {
            int col = nt * 16 + r;
            float bsv = bias_s[col];
            #pragma unroll
            for (int rg = 0; rg < 4; ++rg) {
                int row = m0 + quad * 4 + rg;
                outs[row * LDC + col] = f2b(acc[nt][rg] + bsv);
            }
        }
        __syncthreads();
        bf16* dst = (g == 0) ? qn : (g == 1) ? kn : vn;
        for (int idx = tid; idx < NPB * (HC / 8); idx += 256) {
            int row = idx >> 4, seg = idx & 15;
            int node = n0node + row;
            if (node < NN)
                *reinterpret_cast<uint4*>(dst + (size_t)node * HC + seg * 8) =
                    *reinterpret_cast<const uint4*>(&outs[row * LDC + seg * 8]);
        }
    } else {
        // skip connection: f32 direct stores into d_out
        #pragma unroll
        for (int nt = 0; nt < 8; ++nt) {
            int col = nt * 16 + r;
            float bsv = bias_s[col];
            #pragma unroll
            for (int rg = 0; rg < 4; ++rg) {
                int node = n0node + m0 + quad * 4 + rg;
                if (node < NN) skipv[(size_t)node * HC + col] = acc[nt][rg] + bsv;
            }
        }
    }
}

// ---------------------------------------------------------------------------
// K2 (fused, dst-sorted): per 64-sorted-edge block:
//   e = [cos(rel*wt+bt), msg] @ We  (MFMA)
//   ex = exp(q[dst].(k[src]+e)/8)   (no-max softmax: exact identity)
//   register-accumulate ex*(v+e) per dst-run; atomic flush on dst change.
// v4: +1-deep software prefetch of next-iter kn/vn gathers (hide L2/HBM lat).
// ---------------------------------------------------------------------------
__global__ __launch_bounds__(256) void k2_fused(
    const int* __restrict__ eidx, const int* __restrict__ perm,
    const float* __restrict__ lu, const float* __restrict__ t, const float* __restrict__ msg,
    const float* __restrict__ wtv, const float* __restrict__ btv,
    const bf16* __restrict__ wFe,
    const bf16* __restrict__ qn, const bf16* __restrict__ kn, const bf16* __restrict__ vn,
    float* __restrict__ out_acc, float* __restrict__ denom)
{
    __shared__ __align__(16) bf16 tile[EPB * LDK];  // edge_attr, then aliased e  (17.4 KB)
    __shared__ float wt_s[TDIM], bt_s[TDIM];
    __shared__ float rel_s[EPB];
    __shared__ int src_s[EPB], dst_s[EPB], eid_s[EPB];

    int tid = threadIdx.x;
    int lane = tid & 63, wave = tid >> 6;
    int e0 = blockIdx.x * EPB;   // NE % EPB == 0, no guards needed

    if (tid < TDIM) { wt_s[tid] = wtv[tid]; bt_s[tid] = btv[tid]; }
    if (tid < EPB) {
        int es = perm[e0 + tid];          // original edge id, dst-sorted order
        int s = eidx[es];
        int d = eidx[NE + es];
        src_s[tid] = s; dst_s[tid] = d; eid_s[tid] = es;
        rel_s[tid] = lu[s] - t[es];
    }
    __syncthreads();

    // build edge_attr tile (bf16, A-operand layout); msg half vectorized
    for (int idx = tid; idx < EPB * (EDD / 4); idx += 256) {
        int m = idx >> 5, c4 = idx & 31;
        union { bf16 h[4]; uint2 u; } pk;
        if (c4 < 16) {
            float rv = rel_s[m];
            #pragma unroll
            for (int j = 0; j < 4; ++j) {
                int d = c4 * 4 + j;
                pk.h[j] = f2b(cosf(fmaf(rv, wt_s[d], bt_s[d])));
            }
        } else {
            float4 v = reinterpret_cast<const float4*>(msg)[(size_t)eid_s[m] * (MSGD / 4) + (c4 - 16)];
            pk.h[0] = f2b(v.x); pk.h[1] = f2b(v.y); pk.h[2] = f2b(v.z); pk.h[3] = f2b(v.w);
        }
        *reinterpret_cast<uint2*>(&tile[m * LDK + c4 * 4]) = pk.u;
    }
    __syncthreads();

    int m0 = wave * 16, r = lane & 15, quad = lane >> 4;
    const short8* Bf = reinterpret_cast<const short8*>(wFe);

    floatx4 acc[8];
    #pragma unroll
    for (int i = 0; i < 8; ++i) acc[i] = (floatx4){0.f, 0.f, 0.f, 0.f};

    #pragma unroll
    for (int k0g = 0; k0g < 4; ++k0g) {
        short8 a = *reinterpret_cast<const short8*>(&tile[(m0 + r) * LDK + k0g * 32 + quad * 8]);
        #pragma unroll
        for (int nt = 0; nt < 8; ++nt) {
            short8 b = Bf[(k0g * 8 + nt) * 64 + lane];
            acc[nt] = __builtin_amdgcn_mfma_f32_16x16x32_bf16(a, b, acc[nt], 0, 0, 0);
        }
    }

    // e tile -> LDS, aliased over edge_attr rows (wave-private rows -> safe)
    #pragma unroll
    for (int nt = 0; nt < 8; ++nt) {
        int col = nt * 16 + r;
        #pragma unroll
        for (int rg = 0; rg < 4; ++rg) {
            tile[(m0 + quad * 4 + rg) * LDK + col] = f2b(acc[nt][rg]);
        }
    }

    // ---- fused epilogue with dst-run merging + 1-deep gather prefetch ----
    // lane owns channels {2*lane, 2*lane+1}; lanes 0..31 head0, 32..63 head1
    int half = lane >> 5;
    int cur = dst_s[m0];
    float2 qv = bload2(&qn[(size_t)cur * HC + 2 * lane]);
    int sn0 = src_s[m0];
    float2 kv = bload2(&kn[(size_t)sn0 * HC + 2 * lane]);
    float2 vv = bload2(&vn[(size_t)sn0 * HC + 2 * lane]);
    float a0 = 0.f, a1 = 0.f, aex = 0.f;

    for (int i = 0; i < 16; ++i) {
        int m = m0 + i;
        int dstn = dst_s[m];
        float2 kvc = kv, vvc = vv;
        if (i < 15) {
            int sn = src_s[m + 1];
            kv = bload2(&kn[(size_t)sn * HC + 2 * lane]);
            vv = bload2(&vn[(size_t)sn * HC + 2 * lane]);
        }
        if (dstn != cur) {                      // wave-uniform branch
            float* ob = &out_acc[(size_t)cur * HC + 2 * lane];
            atomicAdd(ob + 0, a0);
            atomicAdd(ob + 1, a1);
            if ((lane & 31) == 0) atomicAdd(&denom[cur * NH + half], aex);
            a0 = a1 = aex = 0.f;
            cur = dstn;
            qv = bload2(&qn[(size_t)cur * HC + 2 * lane]);
        }
        float2 ev = bload2(&tile[m * LDK + 2 * lane]);
        float part = qv.x * (kvc.x + ev.x) + qv.y * (kvc.y + ev.y);
        part += __shfl_xor(part, 1);
        part += __shfl_xor(part, 2);
        part += __shfl_xor(part, 4);
        part += __shfl_xor(part, 8);
        part += __shfl_xor(part, 16);           // 32-lane head group holds dot
        float ex = __expf(part * 0.125f);       // 1/sqrt(64)
        a0 += ex * (vvc.x + ev.x);
        a1 += ex * (vvc.y + ev.y);
        aex += ex;
    }
    // final flush
    {
        float* ob = &out_acc[(size_t)cur * HC + 2 * lane];
        atomicAdd(ob + 0, a0);
        atomicAdd(ob + 1, a1);
        if ((lane & 31) == 0) atomicAdd(&denom[cur * NH + half], aex);
    }
}

// ---------------------------------------------------------------------------
// K5: out = skip (already in d_out) + out_acc / denom
// ---------------------------------------------------------------------------
__global__ __launch_bounds__(256) void k5_final(
    const float* __restrict__ out_acc, const float* __restrict__ denom,
    float* __restrict__ out)
{
    int tid = blockIdx.x * 256 + threadIdx.x;
    if (tid >= NN * HC) return;
    int node = tid >> 7, h = (tid >> 6) & 1;
    out[tid] = out[tid] + out_acc[tid] / (denom[node * NH + h] + 1e-16f);
}

// ---------------------------------------------------------------------------
extern "C" void kernel_launch(void* const* d_in, const int* in_sizes, int n_in,
                              void* d_out, int out_size, void* d_ws, size_t ws_size,
                              hipStream_t stream)
{
    const float* x   = (const float*)d_in[0];
    const float* lu  = (const float*)d_in[1];
    const int*   eidx= (const int*)d_in[2];
    const float* t   = (const float*)d_in[3];
    const float* msg = (const float*)d_in[4];
    const float* wt  = (const float*)d_in[5];
    const float* bt  = (const float*)d_in[6];
    const float* Wq  = (const float*)d_in[7];
    const float* bq  = (const float*)d_in[8];
    const float* Wk  = (const float*)d_in[9];
    const float* bk  = (const float*)d_in[10];
    const float* Wv  = (const float*)d_in[11];
    const float* bv  = (const float*)d_in[12];
    const float* We  = (const float*)d_in[13];
    const float* Wsk = (const float*)d_in[14];
    const float* bsk = (const float*)d_in[15];
    float* out = (float*)d_out;

    // workspace layout (all offsets 16B-aligned)
    char* ws = (char*)d_ws;
    size_t off = 0;
    bf16*  qn      = (bf16*)(ws + off);  off += (size_t)NN * HC * 2;       // 25.6 MB
    bf16*  kn      = (bf16*)(ws + off);  off += (size_t)NN * HC * 2;       // 25.6 MB
    bf16*  vn      = (bf16*)(ws + off);  off += (size_t)NN * HC * 2;       // 25.6 MB
    float* out_acc = (float*)(ws + off); off += (size_t)NN * HC * 4;       // 51.2 MB
    float* denom   = (float*)(ws + off); off += (size_t)NN * NH * 4;       // 0.8 MB
    bf16*  wF      = (bf16*)(ws + off);  off += (size_t)5 * 128 * 128 * 2; // 0.16 MB
    int*   cnt     = (int*)(ws + off);   off += (size_t)NN * 4;            // 0.4 MB (cursor after scan)
    int*   perm    = (int*)(ws + off);   off += (size_t)NE * 4;            // 2.4 MB
    int*   bsum    = (int*)(ws + off);   off += (size_t)128 * 4;           // scan chunk sums

    k0b_frag<<<(NN * NH + 255) / 256, 256, 0, stream>>>(Wq, Wk, Wv, Wsk, We, wF, denom, cnt);

    kh_hist<<<(NE + 255) / 256, 256, 0, stream>>>(eidx, cnt);
    ks_scan_a<<<NSB, 256, 0, stream>>>(cnt, bsum);
    ks_scan_b<<<1, 128, 0, stream>>>(bsum);
    ks_scan_c<<<NSB, 256, 0, stream>>>(cnt, bsum, cnt);   // in-place: cnt -> start offsets
    kp_scatter<<<(NE + 255) / 256, 256, 0, stream>>>(eidx, cnt, perm);

    {
        dim3 g1(4, (NN + NPB - 1) / NPB);
        k1_node_proj<<<g1, 256, 0, stream>>>(
            x, wF, bq, bk, bv, bsk, qn, kn, vn, out, out_acc);
    }

    k2_fused<<<NE / EPB, 256, 0, stream>>>(
        eidx, perm, lu, t, msg, wt, bt, wF + (size_t)4 * 16384,
        qn, kn, vn, out_acc, denom);

    k5_final<<<(NN * HC + 255) / 256, 256, 0, stream>>>(out_acc, denom, out);
}